// Round 1
// baseline (621.354 us; speedup 1.0000x reference)
//
#include <hip/hip_runtime.h>
#include <hip/hip_bf16.h>
#include <math.h>

#define NH 32
#define NKVH 8
#define HD 128

// ws layout (float elements):
//  [0)       qproj   4096
//  [4096)    knew    1024
//  [5120)    vnew    1024
//  [6144)    q_r     4096
//  [10240)   qhash   128 floats region (used as 64 x u64)
//  [10368)   cos tab K*64
//  +K*64     sin tab K*64
//  +K*64     scores  NH*K
//  +NH*K     draft   NH*K (int32)
//  +NH*K     attn_out 4096
#define OFF_QPROJ 0
#define OFF_KNEW  4096
#define OFF_VNEW  5120
#define OFF_QR    6144
#define OFF_QHASH 10240
#define OFF_TAB   10368

__global__ void init_kernel(float* __restrict__ ws, float* __restrict__ out, int K) {
    int idx = blockIdx.x * 256 + threadIdx.x;
    if (idx < K * 64) {
        int pos = idx >> 6, d = idx & 63;
        // reference: inv_freq = 1/theta^(d/64) computed fp32; we use f64 (best effort)
        double inv = exp(-((double)d / 64.0) * log(10000.0));
        double ang = (double)pos * inv;
        ws[OFF_TAB + idx]          = (float)cos(ang);
        ws[OFF_TAB + K * 64 + idx] = (float)sin(ang);
    }
    if (idx < 6144) ws[OFF_QPROJ + idx] = 0.f;   // qkv proj accumulators
    if (idx < 4096) out[idx] = 0.f;              // final output accumulator
}

// hidden(4096) @ [Wq | Wk | Wv] -> proj (6144), split-K with atomics
__global__ __launch_bounds__(256) void qkv_gemv(const float* __restrict__ hidden,
        const float* __restrict__ Wq, const float* __restrict__ Wk,
        const float* __restrict__ Wv, float* __restrict__ ws) {
    __shared__ float hs[256];
    const int tid = threadIdx.x;
    const int col = blockIdx.x * 256 + tid;    // 0..6143
    const int i0  = blockIdx.y * 256;
    hs[tid] = hidden[i0 + tid];
    __syncthreads();
    const float* W; int ld, wcol;
    if (col < 4096)      { W = Wq; ld = 4096; wcol = col; }
    else if (col < 5120) { W = Wk; ld = 1024; wcol = col - 4096; }
    else                 { W = Wv; ld = 1024; wcol = col - 5120; }
    const float* p = W + (size_t)i0 * ld + wcol;
    float a0 = 0.f, a1 = 0.f, a2 = 0.f, a3 = 0.f;
    for (int ii = 0; ii < 256; ii += 4) {
        a0 = fmaf(hs[ii+0], p[0],      a0);
        a1 = fmaf(hs[ii+1], p[ld],     a1);
        a2 = fmaf(hs[ii+2], p[2*ld],   a2);
        a3 = fmaf(hs[ii+3], p[3*ld],   a3);
        p += (size_t)4 * ld;
    }
    atomicAdd(&ws[OFF_QPROJ + col], (a0 + a1) + (a2 + a3));
}

// per head: rope(q), hash(q), pack sign bits; one block per head, 128 threads
__global__ __launch_bounds__(128) void qhash_kernel(const float* __restrict__ hp1,
        const float* __restrict__ hb1, const float* __restrict__ hp2,
        const float* __restrict__ hb2, float* __restrict__ ws, int S) {
    const int h = blockIdx.x, d = threadIdx.x;
    const int K = S + 1;
    __shared__ float X[128], H1[128];
    float q  = ws[OFF_QPROJ + h * 128 + d];
    float qp = ws[OFF_QPROJ + h * 128 + (d ^ 64)];
    const float* cosT = ws + OFF_TAB;
    const float* sinT = cosT + (size_t)K * 64;
    float cs = cosT[(size_t)S * 64 + (d & 63)];
    float sn = sinT[(size_t)S * 64 + (d & 63)];
    float r = (d < 64) ? -qp : qp;
    float qr = q * cs + r * sn;
    X[d] = qr;
    ws[OFF_QR + h * 128 + d] = qr;
    __syncthreads();
    const float* P1 = hp1 + (size_t)h * 16384;
    float t = hb1[h * 128 + d];
    for (int i = 0; i < 128; ++i) t = fmaf(X[i], P1[i * 128 + d], t);
    float u = t / (1.f + expf(-t)) + X[d];
    H1[d] = u;
    __syncthreads();
    const float* P2 = hp2 + (size_t)h * 16384;
    float t2 = hb2[h * 128 + d] + u;
    for (int i = 0; i < 128; ++i) t2 = fmaf(H1[i], P2[i * 128 + d], t2);
    unsigned long long bal = __ballot(t2 > 0.f);
    if ((d & 63) == 0)
        ((unsigned long long*)(ws + OFF_QHASH))[h * 2 + (d >> 6)] = bal;
}

// the big kernel: per (head, 64-key chunk): rope, scores, 2x 128x128 fp32 GEMM
// (hash), sign-pack, popcount draft scores.
__global__ __launch_bounds__(256) void key_kernel(const float* __restrict__ key_cache,
        const float* __restrict__ hp1, const float* __restrict__ hb1,
        const float* __restrict__ hp2, const float* __restrict__ hb2,
        float* __restrict__ ws, int S) {
    const int K  = S + 1;
    const int h  = blockIdx.y;
    const int k0 = blockIdx.x * 64;
    const int tid = threadIdx.x;
    __shared__ float XT[128][68];      // dim-major: XT[d][k], row stride 272B (16B mult)
    __shared__ float Ptile[16][132];   // 16 P-rows staged, row stride 528B
    __shared__ float qv[128];
    __shared__ unsigned int hbits[64][4];

    const float* cosT = ws + OFF_TAB;
    const float* sinT = cosT + (size_t)K * 64;
    float* scores = ws + OFF_TAB + (size_t)2 * K * 64;
    int*   draft  = (int*)(scores + (size_t)NH * K);

    if (tid < 128) qv[tid] = ws[OFF_QR + h * 128 + tid];
    ((unsigned int*)hbits)[tid] = 0u;

    // build rotated keys (fp32), zero-pad invalid
    for (int idx = tid; idx < 64 * 128; idx += 256) {
        int kl = idx >> 7, d = idx & 127;
        int kg = k0 + kl;
        float v = 0.f;
        if (kg < K) {
            const float* row = (kg < S) ? (key_cache + ((size_t)h * S + kg) * 128)
                                        : (ws + OFF_KNEW + (h >> 2) * 128);
            float x = row[d], xp = row[d ^ 64];
            float cs = cosT[(size_t)kg * 64 + (d & 63)];
            float sn = sinT[(size_t)kg * 64 + (d & 63)];
            float r = (d < 64) ? -xp : xp;
            v = x * cs + r * sn;
        }
        XT[d][kl] = v;
    }
    __syncthreads();

    // true attention scores q_r . k_r / sqrt(D)
    if (tid < 64 && (k0 + tid) < K) {
        float s = 0.f;
        for (int d = 0; d < 128; ++d) s = fmaf(qv[d], XT[d][tid], s);
        scores[(size_t)h * K + k0 + tid] = s * 0.08838834764831845f;
    }

    const int jo = tid & 15;   // output cols j0 = jo*8 .. +7
    const int kq = tid >> 4;   // keys k = kq*4 .. +3
    float acc[4][8];

#define GEMM_LOOP(PBASE, SRC2D)                                                   \
    _Pragma("unroll") for (int kk = 0; kk < 4; ++kk)                              \
        _Pragma("unroll") for (int jj = 0; jj < 8; ++jj) acc[kk][jj] = 0.f;       \
    for (int it = 0; it < 8; ++it) {                                              \
        __syncthreads();                                                          \
        {                                                                         \
            const float4* src = (const float4*)((PBASE) + it * 2048);             \
            float4 f0 = src[tid];                                                 \
            float4 f1 = src[tid + 256];                                           \
            int l0 = tid * 4;                                                     \
            *(float4*)&Ptile[l0 >> 7][l0 & 127] = f0;                             \
            int l1 = l0 + 1024;                                                   \
            *(float4*)&Ptile[l1 >> 7][l1 & 127] = f1;                             \
        }                                                                         \
        __syncthreads();                                                          \
        _Pragma("unroll") for (int ii = 0; ii < 16; ++ii) {                       \
            float4 a4 = *(const float4*)&SRC2D[it * 16 + ii][kq << 2];            \
            float4 b0 = *(const float4*)&Ptile[ii][jo << 3];                      \
            float4 b1 = *(const float4*)&Ptile[ii][(jo << 3) + 4];                \
            float av[4] = {a4.x, a4.y, a4.z, a4.w};                               \
            float bv[8] = {b0.x, b0.y, b0.z, b0.w, b1.x, b1.y, b1.z, b1.w};       \
            _Pragma("unroll") for (int kk = 0; kk < 4; ++kk)                      \
                _Pragma("unroll") for (int jj = 0; jj < 8; ++jj)                  \
                    acc[kk][jj] = fmaf(av[kk], bv[jj], acc[kk][jj]);              \
        }                                                                         \
    }                                                                             \
    __syncthreads();

    // GEMM1: t1 = X @ P1 ; h1 = silu(t1 + b1) + x   (in-place into XT)
    const float* P1 = hp1 + (size_t)h * 16384;
    GEMM_LOOP(P1, XT)
    {
        float b1v[8];
#pragma unroll
        for (int jj = 0; jj < 8; ++jj) b1v[jj] = hb1[h * 128 + (jo << 3) + jj];
#pragma unroll
        for (int kk = 0; kk < 4; ++kk) {
            int k = (kq << 2) + kk;
#pragma unroll
            for (int jj = 0; jj < 8; ++jj) {
                int j = (jo << 3) + jj;
                float t = acc[kk][jj] + b1v[jj];
                float x = XT[j][k];
                float u = t / (1.f + expf(-t));   // silu
                XT[j][k] = u + x;                 // exclusive (k,j) owner -> safe in-place
            }
        }
    }
    __syncthreads();

    // GEMM2: t2 = H1 @ P2 ; v = t2 + b2 + h1 ; sign bits
    const float* P2 = hp2 + (size_t)h * 16384;
    GEMM_LOOP(P2, XT)
    {
        float b2v[8];
#pragma unroll
        for (int jj = 0; jj < 8; ++jj) b2v[jj] = hb2[h * 128 + (jo << 3) + jj];
#pragma unroll
        for (int kk = 0; kk < 4; ++kk) {
            int k = (kq << 2) + kk;
            unsigned int bits8 = 0;
#pragma unroll
            for (int jj = 0; jj < 8; ++jj) {
                int j = (jo << 3) + jj;
                float v = acc[kk][jj] + b2v[jj] + XT[j][k];
                if (v > 0.f) bits8 |= (1u << jj);
            }
            atomicOr(&hbits[k][jo >> 2], bits8 << ((jo & 3) * 8));
        }
    }
    __syncthreads();

    // draft = qhash . khash  (exact, via xor+popcount; sign in {-1,+1})
    if (tid < 64 && (k0 + tid) < K) {
        unsigned long long kb0 = (unsigned long long)hbits[tid][0] |
                                 ((unsigned long long)hbits[tid][1] << 32);
        unsigned long long kb1 = (unsigned long long)hbits[tid][2] |
                                 ((unsigned long long)hbits[tid][3] << 32);
        const unsigned long long* qh = (const unsigned long long*)(ws + OFF_QHASH);
        unsigned long long q0 = qh[h * 2], q1 = qh[h * 2 + 1];
        int dot = 128 - 2 * (__popcll(q0 ^ kb0) + __popcll(q1 ^ kb1));
        draft[(size_t)h * K + k0 + tid] = dot;
    }
}

// per head: exact stable top-k selection (histogram + index-ordered tie scan),
// softmax over selected, weighted sum of selected V rows.
__global__ __launch_bounds__(256) void select_kernel(const float* __restrict__ val_cache,
        float* __restrict__ ws, int S, int nrem) {
    const int K = S + 1;
    const int h = blockIdx.x;
    const int tid = threadIdx.x;
    __shared__ int hist[129];
    __shared__ int sel_idx[512];
    __shared__ float red[256];
    __shared__ int wtot[4];
    __shared__ int sh_tval, sh_r, sh_cnt, sh_run;

    float* scoresB = ws + OFF_TAB + (size_t)2 * K * 64;
    const int* draft = (const int*)(scoresB + (size_t)NH * K) + (size_t)h * K;
    const float* sc = scoresB + (size_t)h * K;

    for (int i = tid; i < 129; i += 256) hist[i] = 0;
    if (tid == 0) { sh_cnt = 0; sh_run = 0; }
    __syncthreads();
    for (int k = tid; k < K; k += 256) atomicAdd(&hist[(draft[k] + 128) >> 1], 1);
    __syncthreads();
    if (tid == 0) {
        int cum = 0, tb = 0, r = nrem;
        for (int b = 128; b >= 0; --b) {
            int c = hist[b];
            if (cum + c >= nrem) { tb = b; r = nrem - cum; break; }
            cum += c;
        }
        sh_tval = tb * 2 - 128; sh_r = r;
    }
    __syncthreads();
    const int tval = sh_tval, r = sh_r;
    const int lane = tid & 63, wave = tid >> 6;
    for (int base = 0; base < K; base += 256) {
        int k = base + tid;
        bool valid = (k < K);
        int dv = valid ? draft[k] : -1000;
        bool eq = valid && (dv == tval);
        bool gt = valid && (dv > tval);
        unsigned long long bal = __ballot(eq);
        if (lane == 0) wtot[wave] = __popcll(bal);
        __syncthreads();
        int woff = 0;
        for (int w = 0; w < wave; ++w) woff += wtot[w];
        int rank = sh_run + woff + __popcll(bal & ((1ull << lane) - 1ull));
        bool sel = gt || (eq && (rank < r));     // stable: lowest index wins ties
        if (sel) sel_idx[atomicAdd(&sh_cnt, 1)] = k;
        __syncthreads();
        if (tid == 0) sh_run += wtot[0] + wtot[1] + wtot[2] + wtot[3];
        __syncthreads();
    }
    // softmax max
    float m = -3.402823466e38f;
    for (int li = tid; li < nrem; li += 256) m = fmaxf(m, sc[sel_idx[li]]);
    red[tid] = m; __syncthreads();
    for (int s2 = 128; s2 > 0; s2 >>= 1) {
        if (tid < s2) red[tid] = fmaxf(red[tid], red[tid + s2]);
        __syncthreads();
    }
    m = red[0]; __syncthreads();
    // denominator
    float z = 0.f;
    for (int li = tid; li < nrem; li += 256) z += expf(sc[sel_idx[li]] - m);
    red[tid] = z; __syncthreads();
    for (int s2 = 128; s2 > 0; s2 >>= 1) {
        if (tid < s2) red[tid] += red[tid + s2];
        __syncthreads();
    }
    float Z = red[0]; __syncthreads();
    // weighted sum of selected V rows
    const int half = tid >> 7, d = tid & 127;
    float acc = 0.f;
    for (int li = half; li < nrem; li += 2) {
        int idx = sel_idx[li];
        float w = expf(sc[idx] - m);
        const float* vr = (idx < S) ? (val_cache + ((size_t)h * S + idx) * 128)
                                    : (ws + OFF_VNEW + (h >> 2) * 128);
        acc = fmaf(w, vr[d], acc);
    }
    red[tid] = acc; __syncthreads();
    if (tid < 128) {
        float* ao = ws + OFF_TAB + (size_t)2 * K * 64 + (size_t)2 * NH * K;
        ao[h * 128 + tid] = (red[tid] + red[tid + 128]) / Z;
    }
}

// attn_out(4096) @ Wo(4096x4096) -> out, split-K with atomics
__global__ __launch_bounds__(256) void out_gemv(const float* __restrict__ Wo,
        const float* __restrict__ ws, float* __restrict__ out, int K) {
    __shared__ float hs[256];
    const int tid = threadIdx.x;
    const int col = blockIdx.x * 256 + tid;
    const int i0  = blockIdx.y * 256;
    const float* ao = ws + OFF_TAB + (size_t)2 * K * 64 + (size_t)2 * NH * K;
    hs[tid] = ao[i0 + tid];
    __syncthreads();
    const float* p = Wo + (size_t)i0 * 4096 + col;
    float a0 = 0.f, a1 = 0.f, a2 = 0.f, a3 = 0.f;
    for (int ii = 0; ii < 256; ii += 4) {
        a0 = fmaf(hs[ii+0], p[0],     a0);
        a1 = fmaf(hs[ii+1], p[4096],  a1);
        a2 = fmaf(hs[ii+2], p[8192],  a2);
        a3 = fmaf(hs[ii+3], p[12288], a3);
        p += (size_t)16384;
    }
    atomicAdd(&out[col], (a0 + a1) + (a2 + a3));
}

extern "C" void kernel_launch(void* const* d_in, const int* in_sizes, int n_in,
                              void* d_out, int out_size, void* d_ws, size_t ws_size,
                              hipStream_t stream) {
    const float* hidden = (const float*)d_in[0];
    const float* key_cache = (const float*)d_in[1];
    const float* val_cache = (const float*)d_in[2];
    const float* Wq = (const float*)d_in[3];
    const float* Wk = (const float*)d_in[4];
    const float* Wv = (const float*)d_in[5];
    const float* Wo = (const float*)d_in[6];
    const float* hp1 = (const float*)d_in[7];
    const float* hb1 = (const float*)d_in[8];
    const float* hp2 = (const float*)d_in[9];
    const float* hb2 = (const float*)d_in[10];
    float* out = (float*)d_out;
    float* ws  = (float*)d_ws;

    const int S = in_sizes[1] / (NH * HD);   // 4096
    const int K = S + 1;                      // 4097
    int mn = (K < 128) ? K : 128;
    int nrem = K - (int)((double)K * 0.9);
    if (nrem < mn) nrem = mn;                 // 410

    init_kernel<<<(K * 64 + 255) / 256, 256, 0, stream>>>(ws, out, K);
    qkv_gemv<<<dim3(24, 16), 256, 0, stream>>>(hidden, Wq, Wk, Wv, ws);
    qhash_kernel<<<NH, 128, 0, stream>>>(hp1, hb1, hp2, hb2, ws, S);
    key_kernel<<<dim3((K + 63) / 64, NH), 256, 0, stream>>>(key_cache, hp1, hb1, hp2, hb2, ws, S);
    select_kernel<<<NH, 256, 0, stream>>>(val_cache, ws, S, nrem);
    out_gemv<<<dim3(16, 16), 256, 0, stream>>>(Wo, ws, out, K);
}

// Round 2
// 551.467 us; speedup vs baseline: 1.1267x; 1.1267x over previous
//
#include <hip/hip_runtime.h>
#include <math.h>

#define NH 32
#define NKVH 8
#define HD 128

// ws layout (float elements):
#define OFF_QPROJ 0        // 4096 q | 1024 k | 1024 v
#define OFF_KNEW  4096
#define OFF_VNEW  5120
#define OFF_QR    6144     // 4096
#define OFF_QHASH 10240    // 128 (used as 32x u32 / 16x u64)
#define OFF_TAB   10368    // cos K*64 | sin K*64 | scores NH*K | draft NH*K (int)
                           // | attn 4096 | selidx NH*512 (int) | selw NH*512

__global__ void init_kernel(float* __restrict__ ws, float* __restrict__ out, int K) {
    int idx = blockIdx.x * 256 + threadIdx.x;
    if (idx < K * 64) {
        int pos = idx >> 6, d = idx & 63;
        double inv = exp(-((double)d / 64.0) * log(10000.0));
        double ang = (double)pos * inv;
        double s, c;
        sincos(ang, &s, &c);
        ws[OFF_TAB + idx]          = (float)c;
        ws[OFF_TAB + (size_t)K * 64 + idx] = (float)s;
    }
    if (idx < 6144) ws[OFF_QPROJ + idx] = 0.f;
    if (idx < 4096) out[idx] = 0.f;
    if (idx < 4096) ws[OFF_TAB + 2*(size_t)K*64 + 2*(size_t)NH*K + idx] = 0.f;  // attn accum
}

// hidden(4096) @ [Wq|Wk|Wv] -> qproj(6144). float4 cols, 32-row split-K, atomics.
__global__ __launch_bounds__(256) void qkv_gemv(const float* __restrict__ hidden,
        const float* __restrict__ Wq, const float* __restrict__ Wk,
        const float* __restrict__ Wv, float* __restrict__ ws) {
    __shared__ float hs[32];
    const int tid = threadIdx.x;
    const int col = (blockIdx.x * 256 + tid) * 4;   // 0..6140, group of 4
    const int i0  = blockIdx.y * 32;
    if (tid < 32) hs[tid] = hidden[i0 + tid];
    __syncthreads();
    const float* W; int ld, wcol;
    if (col < 4096)      { W = Wq; ld = 4096; wcol = col; }
    else if (col < 5120) { W = Wk; ld = 1024; wcol = col - 4096; }
    else                 { W = Wv; ld = 1024; wcol = col - 5120; }
    const float* p = W + (size_t)i0 * ld + wcol;
    float4 acc = {0.f, 0.f, 0.f, 0.f};
#pragma unroll 4
    for (int ii = 0; ii < 32; ++ii) {
        float4 w4 = *(const float4*)p;
        float hh = hs[ii];
        acc.x = fmaf(hh, w4.x, acc.x); acc.y = fmaf(hh, w4.y, acc.y);
        acc.z = fmaf(hh, w4.z, acc.z); acc.w = fmaf(hh, w4.w, acc.w);
        p += ld;
    }
    atomicAdd(&ws[OFF_QPROJ + col + 0], acc.x);
    atomicAdd(&ws[OFF_QPROJ + col + 1], acc.y);
    atomicAdd(&ws[OFF_QPROJ + col + 2], acc.z);
    atomicAdd(&ws[OFF_QPROJ + col + 3], acc.w);
}

// per head: rope(q), hash(q), pack sign bits
__global__ __launch_bounds__(128) void qhash_kernel(const float* __restrict__ hp1,
        const float* __restrict__ hb1, const float* __restrict__ hp2,
        const float* __restrict__ hb2, float* __restrict__ ws, int S) {
    const int h = blockIdx.x, d = threadIdx.x;
    const int K = S + 1;
    __shared__ float X[128], H1[128];
    float q  = ws[OFF_QPROJ + h * 128 + d];
    float qp = ws[OFF_QPROJ + h * 128 + (d ^ 64)];
    const float* cosT = ws + OFF_TAB;
    const float* sinT = cosT + (size_t)K * 64;
    float cs = cosT[(size_t)S * 64 + (d & 63)];
    float sn = sinT[(size_t)S * 64 + (d & 63)];
    float r = (d < 64) ? -qp : qp;
    float qr = q * cs + r * sn;
    X[d] = qr;
    ws[OFF_QR + h * 128 + d] = qr;
    __syncthreads();
    const float* P1 = hp1 + (size_t)h * 16384;
    float t = hb1[h * 128 + d];
    for (int i = 0; i < 128; ++i) t = fmaf(X[i], P1[i * 128 + d], t);
    float u = t / (1.f + expf(-t)) + X[d];
    H1[d] = u;
    __syncthreads();
    const float* P2 = hp2 + (size_t)h * 16384;
    float t2 = hb2[h * 128 + d] + u;
    for (int i = 0; i < 128; ++i) t2 = fmaf(H1[i], P2[i * 128 + d], t2);
    unsigned long long bal = __ballot(t2 > 0.f);
    if ((d & 63) == 0)
        ((unsigned long long*)(ws + OFF_QHASH))[h * 2 + (d >> 6)] = bal;
}

// big kernel: 128 keys per block. rope -> scores -> 2x fp32 128x128 GEMM (8x8
// micro-tile, conflict-free rotated LDS, double-buffered P staging) -> sign
// bits -> popcount draft scores.
__global__ __launch_bounds__(256, 2) void key_kernel(const float* __restrict__ key_cache,
        const float* __restrict__ hp1, const float* __restrict__ hb1,
        const float* __restrict__ hp2, const float* __restrict__ hb2,
        float* __restrict__ ws, int S) {
    const int K  = S + 1;
    const int h  = blockIdx.y;
    const int k0 = blockIdx.x * 128;
    const int tid = threadIdx.x;
    const int tx = tid & 15, ty = tid >> 4;          // ty 0..15 (8 keys each), tx 0..15 (cols)

    __shared__ float XK[128 * 132];                  // [k][phys(d)], stride 132
    __shared__ float Pt[2][8 * 128];                 // staged P rows, dbuf
    __shared__ float qv[128];
    __shared__ unsigned int hbits[128][4];

    const float* cosT = ws + OFF_TAB;
    const float* sinT = cosT + (size_t)K * 64;
    float* scores = ws + OFF_TAB + 2 * (size_t)K * 64;
    int*   draft  = (int*)(scores + (size_t)NH * K);

    if (tid < 128) qv[tid] = ws[OFF_QR + h * 128 + tid];
    { unsigned int* hb = &hbits[0][0]; hb[tid] = 0u; hb[tid + 256] = 0u; }

    // rope build: XK[k][phys(d)], phys = (d + 8*(k>>3)) & 127 (bank de-swizzle)
#pragma unroll 4
    for (int it = 0; it < 64; ++it) {
        int idx = it * 256 + tid;
        int k = idx >> 7, d = idx & 127;
        int kg = k0 + k;
        float v = 0.f;
        if (kg < K) {
            const float* row = (kg < S) ? key_cache + ((size_t)h * S + kg) * 128
                                        : ws + OFF_KNEW + (h >> 2) * 128;
            float x = row[d], xp = row[d ^ 64];
            float cs = cosT[(size_t)kg * 64 + (d & 63)];
            float sn = sinT[(size_t)kg * 64 + (d & 63)];
            float r = (d < 64) ? -xp : xp;
            v = x * cs + r * sn;
        }
        XK[k * 132 + ((d + 8 * (k >> 3)) & 127)] = v;
    }
    __syncthreads();

    // scores: each wave does 32 keys, lane-parallel over d, shuffle reduce
    {
        const int wv = tid >> 6, lane = tid & 63;
        float q0 = qv[2 * lane], q1 = qv[2 * lane + 1];
        for (int kk = 0; kk < 32; ++kk) {
            int k = wv * 32 + kk;
            int p = ((2 * lane + 8 * (k >> 3)) & 127);
            float2 xv = *(const float2*)&XK[k * 132 + p];
            float part = fmaf(q0, xv.x, q1 * xv.y);
            for (int off = 32; off; off >>= 1) part += __shfl_down(part, off);
            if (lane == 0 && (k0 + k) < K)
                scores[(size_t)h * K + k0 + k] = part * 0.08838834764831845f;
        }
    }

    float acc[8][8];

#define DO_GEMM(Pglob)                                                            \
    {                                                                             \
        _Pragma("unroll") for (int r = 0; r < 8; ++r)                             \
            _Pragma("unroll") for (int c = 0; c < 8; ++c) acc[r][c] = 0.f;        \
        float4 preg = *(const float4*)((Pglob) + tid * 4);                        \
        for (int ch = 0; ch < 16; ++ch) {                                         \
            *(float4*)&Pt[ch & 1][tid * 4] = preg;                                \
            __syncthreads();                                                      \
            if (ch < 15) preg = *(const float4*)((Pglob) + (ch + 1) * 1024 + tid * 4); \
            _Pragma("unroll") for (int g = 0; g < 2; ++g) {                       \
                const int i0 = ch * 8 + g * 4;                                    \
                float4 a[8];                                                      \
                _Pragma("unroll") for (int r = 0; r < 8; ++r)                     \
                    a[r] = *(const float4*)&XK[(ty * 8 + r) * 132 + ((i0 + 8 * ty) & 127)]; \
                _Pragma("unroll") for (int ii = 0; ii < 4; ++ii) {                \
                    float4 b0 = *(const float4*)&Pt[ch & 1][(g * 4 + ii) * 128 + tx * 4]; \
                    float4 b1 = *(const float4*)&Pt[ch & 1][(g * 4 + ii) * 128 + 64 + tx * 4]; \
                    _Pragma("unroll") for (int r = 0; r < 8; ++r) {               \
                        float av = ((const float*)&a[r])[ii];                     \
                        acc[r][0] = fmaf(av, b0.x, acc[r][0]);                    \
                        acc[r][1] = fmaf(av, b0.y, acc[r][1]);                    \
                        acc[r][2] = fmaf(av, b0.z, acc[r][2]);                    \
                        acc[r][3] = fmaf(av, b0.w, acc[r][3]);                    \
                        acc[r][4] = fmaf(av, b1.x, acc[r][4]);                    \
                        acc[r][5] = fmaf(av, b1.y, acc[r][5]);                    \
                        acc[r][6] = fmaf(av, b1.z, acc[r][6]);                    \
                        acc[r][7] = fmaf(av, b1.w, acc[r][7]);                    \
                    }                                                             \
                }                                                                 \
            }                                                                     \
        }                                                                         \
    }

    // GEMM1: t = X @ P1 ; h1 = silu(t + b1) + x  (in-place into XK)
    const float* P1 = hp1 + (size_t)h * 16384;
    DO_GEMM(P1)
    __syncthreads();   // all XK reads done before in-place update
    {
        float bq[8];
#pragma unroll
        for (int c = 0; c < 8; ++c)
            bq[c] = hb1[h * 128 + (c >> 2) * 64 + tx * 4 + (c & 3)];
#pragma unroll
        for (int r = 0; r < 8; ++r) {
            const int k = ty * 8 + r;
            float* rowp = &XK[k * 132];
            const int rot = 8 * ty;
#pragma unroll
            for (int hf = 0; hf < 2; ++hf) {
                const int p = ((hf * 64 + tx * 4 + rot) & 127);
                float4 xo = *(const float4*)(rowp + p);
                float4 xn; float t;
                t = acc[r][hf*4+0] + bq[hf*4+0]; xn.x = t / (1.f + expf(-t)) + xo.x;
                t = acc[r][hf*4+1] + bq[hf*4+1]; xn.y = t / (1.f + expf(-t)) + xo.y;
                t = acc[r][hf*4+2] + bq[hf*4+2]; xn.z = t / (1.f + expf(-t)) + xo.z;
                t = acc[r][hf*4+3] + bq[hf*4+3]; xn.w = t / (1.f + expf(-t)) + xo.w;
                *(float4*)(rowp + p) = xn;
            }
        }
    }
    __syncthreads();

    // GEMM2: t2 = H1 @ P2 ; v = t2 + b2 + h1 ; sign bits
    const float* P2 = hp2 + (size_t)h * 16384;
    DO_GEMM(P2)
    {
        float bq[8];
#pragma unroll
        for (int c = 0; c < 8; ++c)
            bq[c] = hb2[h * 128 + (c >> 2) * 64 + tx * 4 + (c & 3)];
#pragma unroll
        for (int r = 0; r < 8; ++r) {
            const int k = ty * 8 + r;
            const float* rowp = &XK[k * 132];
            const int rot = 8 * ty;
            unsigned m0 = 0, m1 = 0;
#pragma unroll
            for (int hf = 0; hf < 2; ++hf) {
                const int p = ((hf * 64 + tx * 4 + rot) & 127);
                float4 h1 = *(const float4*)(rowp + p);
                unsigned mm = 0;
                if (acc[r][hf*4+0] + bq[hf*4+0] + h1.x > 0.f) mm |= 1u;
                if (acc[r][hf*4+1] + bq[hf*4+1] + h1.y > 0.f) mm |= 2u;
                if (acc[r][hf*4+2] + bq[hf*4+2] + h1.z > 0.f) mm |= 4u;
                if (acc[r][hf*4+3] + bq[hf*4+3] + h1.w > 0.f) mm |= 8u;
                if (hf == 0) m0 = mm; else m1 = mm;
            }
            const int sh = (tx * 4) & 31;
            atomicOr(&hbits[k][tx >> 3],     m0 << sh);
            atomicOr(&hbits[k][2 + (tx >> 3)], m1 << sh);
        }
    }
    __syncthreads();

    if (tid < 128) {
        int kg = k0 + tid;
        if (kg < K) {
            const unsigned* qh = (const unsigned*)(ws + OFF_QHASH) + h * 4;
            int ham = __popc(hbits[tid][0] ^ qh[0]) + __popc(hbits[tid][1] ^ qh[1])
                    + __popc(hbits[tid][2] ^ qh[2]) + __popc(hbits[tid][3] ^ qh[3]);
            draft[(size_t)h * K + kg] = 128 - 2 * ham;
        }
    }
#undef DO_GEMM
}

// per head: exact stable top-k (histogram + index-ordered tie scan), then write
// selected indices + softmax weights.
__global__ __launch_bounds__(256) void select_kernel(float* __restrict__ ws, int S, int nrem) {
    const int K = S + 1;
    const int h = blockIdx.x;
    const int tid = threadIdx.x;
    __shared__ int hist[129];
    __shared__ int sel_idx[512];
    __shared__ float red[256];
    __shared__ int wtot[4];
    __shared__ int sh_tval, sh_r, sh_cnt, sh_run;

    float* scoresB = ws + OFF_TAB + 2 * (size_t)K * 64;
    const int* draft = (const int*)(scoresB + (size_t)NH * K) + (size_t)h * K;
    const float* sc = scoresB + (size_t)h * K;
    float* attn = scoresB + 2 * (size_t)NH * K;
    int*   selidx_g = (int*)(attn + 4096) + h * 512;
    float* selw_g   = (attn + 4096 + NH * 512) + h * 512;

    for (int i = tid; i < 129; i += 256) hist[i] = 0;
    if (tid == 0) { sh_cnt = 0; sh_run = 0; }
    __syncthreads();
    for (int k = tid; k < K; k += 256) atomicAdd(&hist[(draft[k] + 128) >> 1], 1);
    __syncthreads();
    if (tid == 0) {
        int cum = 0, tb = 0, r = nrem;
        for (int b = 128; b >= 0; --b) {
            int c = hist[b];
            if (cum + c >= nrem) { tb = b; r = nrem - cum; break; }
            cum += c;
        }
        sh_tval = tb * 2 - 128; sh_r = r;
    }
    __syncthreads();
    const int tval = sh_tval, r = sh_r;
    const int lane = tid & 63, wave = tid >> 6;
    for (int base = 0; base < K; base += 256) {
        int k = base + tid;
        bool valid = (k < K);
        int dv = valid ? draft[k] : -1000;
        bool eq = valid && (dv == tval);
        bool gt = valid && (dv > tval);
        unsigned long long bal = __ballot(eq);
        if (lane == 0) wtot[wave] = __popcll(bal);
        __syncthreads();
        int woff = 0;
        for (int w = 0; w < wave; ++w) woff += wtot[w];
        int rank = sh_run + woff + __popcll(bal & ((1ull << lane) - 1ull));
        bool sel = gt || (eq && (rank < r));
        if (sel) sel_idx[atomicAdd(&sh_cnt, 1)] = k;
        __syncthreads();
        if (tid == 0) sh_run += wtot[0] + wtot[1] + wtot[2] + wtot[3];
        __syncthreads();
    }
    float m = -3.402823466e38f;
    for (int li = tid; li < nrem; li += 256) m = fmaxf(m, sc[sel_idx[li]]);
    red[tid] = m; __syncthreads();
    for (int s2 = 128; s2 > 0; s2 >>= 1) {
        if (tid < s2) red[tid] = fmaxf(red[tid], red[tid + s2]);
        __syncthreads();
    }
    m = red[0]; __syncthreads();
    float z = 0.f;
    for (int li = tid; li < nrem; li += 256) z += expf(sc[sel_idx[li]] - m);
    red[tid] = z; __syncthreads();
    for (int s2 = 128; s2 > 0; s2 >>= 1) {
        if (tid < s2) red[tid] += red[tid + s2];
        __syncthreads();
    }
    float Z = red[0]; __syncthreads();
    for (int li = tid; li < nrem; li += 256) {
        int idx = sel_idx[li];
        selidx_g[li] = idx;
        selw_g[li] = expf(sc[idx] - m) / Z;
    }
}

// weighted V gather: grid (NH, 8); 16 independent index streams; atomic accum.
__global__ __launch_bounds__(256) void gather_kernel(const float* __restrict__ val_cache,
        float* __restrict__ ws, int S, int nrem) {
    const int K = S + 1;
    const int h = blockIdx.x, g = blockIdx.y;
    const int tid = threadIdx.x;
    const int d = tid & 127, pr = tid >> 7;
    float* scoresB = ws + OFF_TAB + 2 * (size_t)K * 64;
    float* attn = scoresB + 2 * (size_t)NH * K;
    const int*   selidx_g = (const int*)(attn + 4096) + h * 512;
    const float* selw_g   = (attn + 4096 + NH * 512) + h * 512;
    float acc = 0.f;
    for (int li = g * 2 + pr; li < nrem; li += 16) {
        int idx = selidx_g[li];
        float w = selw_g[li];
        const float* vr = (idx < S) ? val_cache + ((size_t)h * S + idx) * 128
                                    : ws + OFF_VNEW + (h >> 2) * 128;
        acc = fmaf(w, vr[d], acc);
    }
    atomicAdd(&attn[h * 128 + d], acc);
}

// attn(4096) @ Wo(4096x4096) -> out. float4 cols, 32-row split-K, atomics.
__global__ __launch_bounds__(256) void out_gemv(const float* __restrict__ Wo,
        const float* __restrict__ ws, float* __restrict__ out, int K) {
    __shared__ float hs[32];
    const int tid = threadIdx.x;
    const int col = (blockIdx.x * 256 + tid) * 4;
    const int i0  = blockIdx.y * 32;
    const float* ao = ws + OFF_TAB + 2 * (size_t)K * 64 + 2 * (size_t)NH * K;
    if (tid < 32) hs[tid] = ao[i0 + tid];
    __syncthreads();
    const float* p = Wo + (size_t)i0 * 4096 + col;
    float4 acc = {0.f, 0.f, 0.f, 0.f};
#pragma unroll 4
    for (int ii = 0; ii < 32; ++ii) {
        float4 w4 = *(const float4*)p;
        float hh = hs[ii];
        acc.x = fmaf(hh, w4.x, acc.x); acc.y = fmaf(hh, w4.y, acc.y);
        acc.z = fmaf(hh, w4.z, acc.z); acc.w = fmaf(hh, w4.w, acc.w);
        p += 4096;
    }
    atomicAdd(&out[col + 0], acc.x);
    atomicAdd(&out[col + 1], acc.y);
    atomicAdd(&out[col + 2], acc.z);
    atomicAdd(&out[col + 3], acc.w);
}

extern "C" void kernel_launch(void* const* d_in, const int* in_sizes, int n_in,
                              void* d_out, int out_size, void* d_ws, size_t ws_size,
                              hipStream_t stream) {
    const float* hidden = (const float*)d_in[0];
    const float* key_cache = (const float*)d_in[1];
    const float* val_cache = (const float*)d_in[2];
    const float* Wq = (const float*)d_in[3];
    const float* Wk = (const float*)d_in[4];
    const float* Wv = (const float*)d_in[5];
    const float* Wo = (const float*)d_in[6];
    const float* hp1 = (const float*)d_in[7];
    const float* hb1 = (const float*)d_in[8];
    const float* hp2 = (const float*)d_in[9];
    const float* hb2 = (const float*)d_in[10];
    float* out = (float*)d_out;
    float* ws  = (float*)d_ws;

    const int S = in_sizes[1] / (NH * HD);   // 4096
    const int K = S + 1;                      // 4097
    int mn = (K < 128) ? K : 128;
    int nrem = K - (int)((double)K * 0.9);
    if (nrem < mn) nrem = mn;                 // 410

    init_kernel<<<(K * 64 + 255) / 256, 256, 0, stream>>>(ws, out, K);
    qkv_gemv<<<dim3(6, 128), 256, 0, stream>>>(hidden, Wq, Wk, Wv, ws);
    qhash_kernel<<<NH, 128, 0, stream>>>(hp1, hb1, hp2, hb2, ws, S);
    key_kernel<<<dim3((K + 127) / 128, NH), 256, 0, stream>>>(key_cache, hp1, hb1, hp2, hb2, ws, S);
    select_kernel<<<NH, 256, 0, stream>>>(ws, S, nrem);
    gather_kernel<<<dim3(NH, 8), 256, 0, stream>>>(val_cache, ws, S, nrem);
    out_gemv<<<dim3(4, 128), 256, 0, stream>>>(Wo, ws, out, K);
}

// Round 3
// 377.331 us; speedup vs baseline: 1.6467x; 1.4615x over previous
//
#include <hip/hip_runtime.h>
#include <math.h>

#define NH 32
#define NKVH 8
#define HD 128

typedef _Float16 half8 __attribute__((ext_vector_type(8)));
typedef float f32x4 __attribute__((ext_vector_type(4)));

// ws layout (float elements):
#define OFF_QPROJ 0        // 4096 q | 1024 k | 1024 v
#define OFF_KNEW  4096
#define OFF_VNEW  5120
#define OFF_QR    6144     // 4096
#define OFF_QHASH 10240    // 128 (32x u32)
#define OFF_TAB   10368    // cos K*64 | sin K*64
// OFF_SCORES = OFF_TAB + 2*K*64        (NH*K floats)
// OFF_DRAFT  = OFF_SCORES + NH*K       (NH*K int)
// OFF_ATTN   = OFF_DRAFT + NH*K        (4096)
// OFF_SELIDX = OFF_ATTN + 4096         (NH*512 int)
// OFF_SELW   = OFF_SELIDX + NH*512     (NH*512)
// OFF_PT16   = OFF_SELW + NH*512       (NH*2*16384 fp16 = NH*2*8192 floats)

__global__ void init_kernel(float* __restrict__ ws, float* __restrict__ out, int K) {
    int idx = blockIdx.x * 256 + threadIdx.x;
    if (idx < K * 64) {
        int pos = idx >> 6, d = idx & 63;
        double inv = exp(-((double)d / 64.0) * log(10000.0));
        double ang = (double)pos * inv;
        double s, c;
        sincos(ang, &s, &c);
        ws[OFF_TAB + idx]                  = (float)c;
        ws[OFF_TAB + (size_t)K * 64 + idx] = (float)s;
    }
    if (idx < 6144) ws[OFF_QPROJ + idx] = 0.f;
    if (idx < 4096) out[idx] = 0.f;
    size_t off_attn = OFF_TAB + 2 * (size_t)K * 64 + 2 * (size_t)NH * K;
    if (idx < 4096) ws[off_attn + idx] = 0.f;
}

// Pre-transpose hash weights into MFMA B-fragment-linear fp16:
// PT16[h][mat][kstep(4)][ntile(8)][lane(64)][j(8)],
// element = P[h][k = ks*32 + (lane>>4)*8 + j][n = nt*16 + (lane&15)]
__global__ __launch_bounds__(256) void pt16_prep(const float* __restrict__ hp1,
        const float* __restrict__ hp2, float* __restrict__ ws, int K) {
    const int tg  = blockIdx.x * 256 + threadIdx.x;   // 0..2047
    const int h   = blockIdx.y >> 1, mat = blockIdx.y & 1;
    const int lane = tg & 63, nt = (tg >> 6) & 7, ks = tg >> 9;
    const int kbase = ks * 32 + ((tg >> 4) & 3) * 8;
    const int n = nt * 16 + (tg & 15);
    const float* P = (mat ? hp2 : hp1) + (size_t)h * 16384;
    half8 v;
#pragma unroll
    for (int j = 0; j < 8; ++j) v[j] = (_Float16)P[(size_t)(kbase + j) * 128 + n];
    size_t off_pt = OFF_TAB + 2 * (size_t)K * 64 + 2 * (size_t)NH * K + 4096 + 2 * (size_t)NH * 512;
    ((half8*)(ws + off_pt))[(size_t)(h * 2 + mat) * 2048 + tg] = v;
}

// hidden(4096) @ [Wq|Wk|Wv] -> qproj(6144). float4 cols, 32-row split-K, atomics.
__global__ __launch_bounds__(256) void qkv_gemv(const float* __restrict__ hidden,
        const float* __restrict__ Wq, const float* __restrict__ Wk,
        const float* __restrict__ Wv, float* __restrict__ ws) {
    __shared__ float hs[32];
    const int tid = threadIdx.x;
    const int col = (blockIdx.x * 256 + tid) * 4;
    const int i0  = blockIdx.y * 32;
    if (tid < 32) hs[tid] = hidden[i0 + tid];
    __syncthreads();
    const float* W; int ld, wcol;
    if (col < 4096)      { W = Wq; ld = 4096; wcol = col; }
    else if (col < 5120) { W = Wk; ld = 1024; wcol = col - 4096; }
    else                 { W = Wv; ld = 1024; wcol = col - 5120; }
    const float* p = W + (size_t)i0 * ld + wcol;
    float4 acc = {0.f, 0.f, 0.f, 0.f};
#pragma unroll 4
    for (int ii = 0; ii < 32; ++ii) {
        float4 w4 = *(const float4*)p;
        float hh = hs[ii];
        acc.x = fmaf(hh, w4.x, acc.x); acc.y = fmaf(hh, w4.y, acc.y);
        acc.z = fmaf(hh, w4.z, acc.z); acc.w = fmaf(hh, w4.w, acc.w);
        p += ld;
    }
    atomicAdd(&ws[OFF_QPROJ + col + 0], acc.x);
    atomicAdd(&ws[OFF_QPROJ + col + 1], acc.y);
    atomicAdd(&ws[OFF_QPROJ + col + 2], acc.z);
    atomicAdd(&ws[OFF_QPROJ + col + 3], acc.w);
}

// per head: rope(q), hash(q) in fp32, pack sign bits
__global__ __launch_bounds__(128) void qhash_kernel(const float* __restrict__ hp1,
        const float* __restrict__ hb1, const float* __restrict__ hp2,
        const float* __restrict__ hb2, float* __restrict__ ws, int S) {
    const int h = blockIdx.x, d = threadIdx.x;
    const int K = S + 1;
    __shared__ float X[128], H1[128];
    float q  = ws[OFF_QPROJ + h * 128 + d];
    float qp = ws[OFF_QPROJ + h * 128 + (d ^ 64)];
    const float* cosT = ws + OFF_TAB;
    const float* sinT = cosT + (size_t)K * 64;
    float cs = cosT[(size_t)S * 64 + (d & 63)];
    float sn = sinT[(size_t)S * 64 + (d & 63)];
    float r = (d < 64) ? -qp : qp;
    float qr = q * cs + r * sn;
    X[d] = qr;
    ws[OFF_QR + h * 128 + d] = qr;
    __syncthreads();
    const float* P1 = hp1 + (size_t)h * 16384;
    float t = hb1[h * 128 + d];
    for (int i = 0; i < 128; ++i) t = fmaf(X[i], P1[i * 128 + d], t);
    float u = t / (1.f + expf(-t)) + X[d];
    H1[d] = u;
    __syncthreads();
    const float* P2 = hp2 + (size_t)h * 16384;
    float t2 = hb2[h * 128 + d] + u;
    for (int i = 0; i < 128; ++i) t2 = fmaf(H1[i], P2[i * 128 + d], t2);
    unsigned long long bal = __ballot(t2 > 0.f);
    if ((d & 63) == 0)
        ((unsigned long long*)(ws + OFF_QHASH))[h * 2 + (d >> 6)] = bal;
}

// MFMA key kernel: 64 keys/block. rope(fp32)+scores(fp32) -> GEMM1/2 via
// mfma_f32_16x16x32_f16 (A=keys fp16, B=pre-fragmented weights fp16, C fp32),
// fp32 residual path kept in LDS XF -> sign bits -> popcount draft.
__global__ __launch_bounds__(256, 2) void key_kernel(const float* __restrict__ key_cache,
        const float* __restrict__ hb1, const float* __restrict__ hb2,
        float* __restrict__ ws, int S) {
    const int K  = S + 1;
    const int h  = blockIdx.y;
    const int k0 = blockIdx.x * 64;
    const int tid = threadIdx.x;
    const int wv = tid >> 6, lane = tid & 63;

    __shared__ float    XF[64 * 132];      // fp32 rotated keys / h1 (residual path)
    __shared__ _Float16 XH[64 * 136];      // fp16 copy for MFMA A
    __shared__ _Float16 BST[2 * 4096];     // B-fragment chunk, double buffered
    __shared__ unsigned short HB[64 * 8];  // sign bits per key (8x16)
    __shared__ float    QV[128];

    const float* cosT = ws + OFF_TAB;
    const float* sinT = cosT + (size_t)K * 64;
    float* scores = ws + OFF_TAB + 2 * (size_t)K * 64;
    int*   draft  = (int*)(scores + (size_t)NH * K);
    size_t off_pt = OFF_TAB + 2 * (size_t)K * 64 + 2 * (size_t)NH * K + 4096 + 2 * (size_t)NH * 512;
    const _Float16* PT1 = (const _Float16*)(ws + off_pt) + (size_t)(h * 2 + 0) * 16384;
    const _Float16* PT2 = (const _Float16*)(ws + off_pt) + (size_t)(h * 2 + 1) * 16384;

    if (tid < 128) QV[tid] = ws[OFF_QR + h * 128 + tid];

    // ---- rope: thread = (key = tid>>2, qq = tid&3), d0 = qq*16 ----
    const int key = tid >> 2, qq = tid & 3, d0 = qq * 16;
    const int kg = k0 + key;
    float lo[16], hi[16];
    if (kg < K) {
        const float* row = (kg < S) ? key_cache + ((size_t)h * S + kg) * 128
                                    : ws + OFF_KNEW + (h >> 2) * 128;
#pragma unroll
        for (int i4 = 0; i4 < 4; ++i4) {
            float4 xa = *(const float4*)(row + d0 + i4 * 4);
            float4 xb = *(const float4*)(row + 64 + d0 + i4 * 4);
            float4 cc = *(const float4*)(cosT + (size_t)kg * 64 + d0 + i4 * 4);
            float4 ss = *(const float4*)(sinT + (size_t)kg * 64 + d0 + i4 * 4);
            lo[i4*4+0] = xa.x * cc.x - xb.x * ss.x;  hi[i4*4+0] = xb.x * cc.x + xa.x * ss.x;
            lo[i4*4+1] = xa.y * cc.y - xb.y * ss.y;  hi[i4*4+1] = xb.y * cc.y + xa.y * ss.y;
            lo[i4*4+2] = xa.z * cc.z - xb.z * ss.z;  hi[i4*4+2] = xb.z * cc.z + xa.z * ss.z;
            lo[i4*4+3] = xa.w * cc.w - xb.w * ss.w;  hi[i4*4+3] = xb.w * cc.w + xa.w * ss.w;
        }
    } else {
#pragma unroll
        for (int i = 0; i < 16; ++i) { lo[i] = 0.f; hi[i] = 0.f; }
    }
#pragma unroll
    for (int i = 0; i < 16; ++i) {
        XF[key * 132 + d0 + i]      = lo[i];
        XF[key * 132 + 64 + d0 + i] = hi[i];
        XH[key * 136 + d0 + i]      = (_Float16)lo[i];
        XH[key * 136 + 64 + d0 + i] = (_Float16)hi[i];
    }
    __syncthreads();   // QV + XF/XH visible

    // ---- true attention scores (fp32, from registers) ----
    {
        float part = 0.f;
#pragma unroll
        for (int i = 0; i < 16; ++i)
            part = fmaf(QV[d0 + i], lo[i], fmaf(QV[64 + d0 + i], hi[i], part));
        part += __shfl_xor(part, 1);
        part += __shfl_xor(part, 2);
        if (qq == 0 && kg < K) scores[(size_t)h * K + kg] = part * 0.08838834764831845f;
    }

    // biases for this lane's 8 ntile columns
    float b1v[8], b2v[8];
#pragma unroll
    for (int nt = 0; nt < 8; ++nt) {
        b1v[nt] = hb1[h * 128 + nt * 16 + (lane & 15)];
        b2v[nt] = hb2[h * 128 + nt * 16 + (lane & 15)];
    }

    f32x4 acc[8];
    const int m = lane & 15, quad = lane >> 4;

#define GEMM_MFMA(PT)                                                              \
    {                                                                              \
        _Pragma("unroll") for (int nt = 0; nt < 8; ++nt)                           \
            acc[nt] = (f32x4){0.f, 0.f, 0.f, 0.f};                                 \
        const half8* src = (const half8*)(PT);                                     \
        half8 pre0 = src[tid * 2], pre1 = src[tid * 2 + 1];                        \
        for (int c = 0; c < 4; ++c) {                                              \
            half8* dst = (half8*)&BST[(c & 1) * 4096];                             \
            dst[tid * 2] = pre0; dst[tid * 2 + 1] = pre1;                          \
            __syncthreads();                                                       \
            if (c < 3) {                                                           \
                pre0 = src[(c + 1) * 512 + tid * 2];                               \
                pre1 = src[(c + 1) * 512 + tid * 2 + 1];                           \
            }                                                                      \
            half8 afrag = *(const half8*)&XH[(wv * 16 + m) * 136 + c * 32 + quad * 8]; \
            _Pragma("unroll") for (int nt = 0; nt < 8; ++nt) {                     \
                half8 bfrag = *(const half8*)&BST[(c & 1) * 4096 + nt * 512 + lane * 8]; \
                acc[nt] = __builtin_amdgcn_mfma_f32_16x16x32_f16(afrag, bfrag, acc[nt], 0, 0, 0); \
            }                                                                      \
        }                                                                          \
    }

    // ---- GEMM1: t1 = X@P1 ; h1 = silu(t1+b1) + x ----
    GEMM_MFMA(PT1)
#pragma unroll
    for (int nt = 0; nt < 8; ++nt) {
        const int n = nt * 16 + m;
#pragma unroll
        for (int r = 0; r < 4; ++r) {
            const int kk = wv * 16 + quad * 4 + r;
            float t = acc[nt][r] + b1v[nt];
            float x = XF[kk * 132 + n];
            float h1v = t / (1.f + expf(-t)) + x;
            XF[kk * 132 + n] = h1v;                 // fp32 residual for GEMM2 epilogue
            XH[kk * 136 + n] = (_Float16)h1v;       // fp16 A-operand for GEMM2
        }
    }
    // no barrier needed: each wave reads/writes only its own 16-key rows

    // ---- GEMM2: t2 = H1@P2 + b2 + h1 ; sign bits ----
    GEMM_MFMA(PT2)
#pragma unroll
    for (int nt = 0; nt < 8; ++nt) {
        const int n = nt * 16 + m;
#pragma unroll
        for (int r = 0; r < 4; ++r) {
            const int kk = wv * 16 + quad * 4 + r;
            float t2 = acc[nt][r] + b2v[nt] + XF[kk * 132 + n];
            unsigned long long bal = __ballot(t2 > 0.f);
            if (m == 0) {
                unsigned short chunk = (unsigned short)((bal >> (quad * 16)) & 0xFFFFull);
                HB[(wv * 16 + quad * 4 + r) * 8 + nt] = chunk;
            }
        }
    }
    __syncthreads();

    // ---- draft scores via popcount ----
    if (tid < 64) {
        int kgd = k0 + tid;
        if (kgd < K) {
            const unsigned short* hbp = &HB[tid * 8];
            unsigned w0 = (unsigned)hbp[0] | ((unsigned)hbp[1] << 16);
            unsigned w1 = (unsigned)hbp[2] | ((unsigned)hbp[3] << 16);
            unsigned w2 = (unsigned)hbp[4] | ((unsigned)hbp[5] << 16);
            unsigned w3 = (unsigned)hbp[6] | ((unsigned)hbp[7] << 16);
            const unsigned* qh = (const unsigned*)(ws + OFF_QHASH) + h * 4;
            int ham = __popc(w0 ^ qh[0]) + __popc(w1 ^ qh[1])
                    + __popc(w2 ^ qh[2]) + __popc(w3 ^ qh[3]);
            draft[(size_t)h * K + kgd] = 128 - 2 * ham;
        }
    }
#undef GEMM_MFMA
}

// per head: exact stable top-k (histogram + index-ordered tie scan), write
// selected indices + softmax weights.
__global__ __launch_bounds__(256) void select_kernel(float* __restrict__ ws, int S, int nrem) {
    const int K = S + 1;
    const int h = blockIdx.x;
    const int tid = threadIdx.x;
    __shared__ int hist[129];
    __shared__ int sel_idx[512];
    __shared__ float red[256];
    __shared__ int wtot[4];
    __shared__ int sh_tval, sh_r, sh_cnt, sh_run;

    float* scoresB = ws + OFF_TAB + 2 * (size_t)K * 64;
    const int* draft = (const int*)(scoresB + (size_t)NH * K) + (size_t)h * K;
    const float* sc = scoresB + (size_t)h * K;
    float* attn = scoresB + 2 * (size_t)NH * K;
    int*   selidx_g = (int*)(attn + 4096) + h * 512;
    float* selw_g   = (attn + 4096 + NH * 512) + h * 512;

    for (int i = tid; i < 129; i += 256) hist[i] = 0;
    if (tid == 0) { sh_cnt = 0; sh_run = 0; }
    __syncthreads();
    for (int k = tid; k < K; k += 256) atomicAdd(&hist[(draft[k] + 128) >> 1], 1);
    __syncthreads();
    if (tid == 0) {
        int cum = 0, tb = 0, r = nrem;
        for (int b = 128; b >= 0; --b) {
            int c = hist[b];
            if (cum + c >= nrem) { tb = b; r = nrem - cum; break; }
            cum += c;
        }
        sh_tval = tb * 2 - 128; sh_r = r;
    }
    __syncthreads();
    const int tval = sh_tval, r = sh_r;
    const int lane = tid & 63, wave = tid >> 6;
    for (int base = 0; base < K; base += 256) {
        int k = base + tid;
        bool valid = (k < K);
        int dv = valid ? draft[k] : -1000;
        bool eq = valid && (dv == tval);
        bool gt = valid && (dv > tval);
        unsigned long long bal = __ballot(eq);
        if (lane == 0) wtot[wave] = __popcll(bal);
        __syncthreads();
        int woff = 0;
        for (int w = 0; w < wave; ++w) woff += wtot[w];
        int rank = sh_run + woff + __popcll(bal & ((1ull << lane) - 1ull));
        bool sel = gt || (eq && (rank < r));
        if (sel) sel_idx[atomicAdd(&sh_cnt, 1)] = k;
        __syncthreads();
        if (tid == 0) sh_run += wtot[0] + wtot[1] + wtot[2] + wtot[3];
        __syncthreads();
    }
    float mmax = -3.402823466e38f;
    for (int li = tid; li < nrem; li += 256) mmax = fmaxf(mmax, sc[sel_idx[li]]);
    red[tid] = mmax; __syncthreads();
    for (int s2 = 128; s2 > 0; s2 >>= 1) {
        if (tid < s2) red[tid] = fmaxf(red[tid], red[tid + s2]);
        __syncthreads();
    }
    mmax = red[0]; __syncthreads();
    float z = 0.f;
    for (int li = tid; li < nrem; li += 256) z += expf(sc[sel_idx[li]] - mmax);
    red[tid] = z; __syncthreads();
    for (int s2 = 128; s2 > 0; s2 >>= 1) {
        if (tid < s2) red[tid] += red[tid + s2];
        __syncthreads();
    }
    float Z = red[0]; __syncthreads();
    for (int li = tid; li < nrem; li += 256) {
        int idx = sel_idx[li];
        selidx_g[li] = idx;
        selw_g[li] = expf(sc[idx] - mmax) / Z;
    }
}

// weighted V gather: grid (NH, 8); 16 independent index streams; atomic accum.
__global__ __launch_bounds__(256) void gather_kernel(const float* __restrict__ val_cache,
        float* __restrict__ ws, int S, int nrem) {
    const int K = S + 1;
    const int h = blockIdx.x, g = blockIdx.y;
    const int tid = threadIdx.x;
    const int d = tid & 127, pr = tid >> 7;
    float* scoresB = ws + OFF_TAB + 2 * (size_t)K * 64;
    float* attn = scoresB + 2 * (size_t)NH * K;
    const int*   selidx_g = (const int*)(attn + 4096) + h * 512;
    const float* selw_g   = (attn + 4096 + NH * 512) + h * 512;
    float acc = 0.f;
    for (int li = g * 2 + pr; li < nrem; li += 16) {
        int idx = selidx_g[li];
        float w = selw_g[li];
        const float* vr = (idx < S) ? val_cache + ((size_t)h * S + idx) * 128
                                    : ws + OFF_VNEW + (h >> 2) * 128;
        acc = fmaf(w, vr[d], acc);
    }
    atomicAdd(&attn[h * 128 + d], acc);
}

// attn(4096) @ Wo(4096x4096) -> out. float4 cols, 32-row split-K, atomics.
__global__ __launch_bounds__(256) void out_gemv(const float* __restrict__ Wo,
        const float* __restrict__ ws, float* __restrict__ out, int K) {
    __shared__ float hs[32];
    const int tid = threadIdx.x;
    const int col = (blockIdx.x * 256 + tid) * 4;
    const int i0  = blockIdx.y * 32;
    const float* ao = ws + OFF_TAB + 2 * (size_t)K * 64 + 2 * (size_t)NH * K;
    if (tid < 32) hs[tid] = ao[i0 + tid];
    __syncthreads();
    const float* p = Wo + (size_t)i0 * 4096 + col;
    float4 acc = {0.f, 0.f, 0.f, 0.f};
#pragma unroll 4
    for (int ii = 0; ii < 32; ++ii) {
        float4 w4 = *(const float4*)p;
        float hh = hs[ii];
        acc.x = fmaf(hh, w4.x, acc.x); acc.y = fmaf(hh, w4.y, acc.y);
        acc.z = fmaf(hh, w4.z, acc.z); acc.w = fmaf(hh, w4.w, acc.w);
        p += 4096;
    }
    atomicAdd(&out[col + 0], acc.x);
    atomicAdd(&out[col + 1], acc.y);
    atomicAdd(&out[col + 2], acc.z);
    atomicAdd(&out[col + 3], acc.w);
}

extern "C" void kernel_launch(void* const* d_in, const int* in_sizes, int n_in,
                              void* d_out, int out_size, void* d_ws, size_t ws_size,
                              hipStream_t stream) {
    const float* hidden = (const float*)d_in[0];
    const float* key_cache = (const float*)d_in[1];
    const float* val_cache = (const float*)d_in[2];
    const float* Wq = (const float*)d_in[3];
    const float* Wk = (const float*)d_in[4];
    const float* Wv = (const float*)d_in[5];
    const float* Wo = (const float*)d_in[6];
    const float* hp1 = (const float*)d_in[7];
    const float* hb1 = (const float*)d_in[8];
    const float* hp2 = (const float*)d_in[9];
    const float* hb2 = (const float*)d_in[10];
    float* out = (float*)d_out;
    float* ws  = (float*)d_ws;

    const int S = in_sizes[1] / (NH * HD);   // 4096
    const int K = S + 1;                      // 4097
    int mn = (K < 128) ? K : 128;
    int nrem = K - (int)((double)K * 0.9);
    if (nrem < mn) nrem = mn;                 // 410

    init_kernel<<<(K * 64 + 255) / 256, 256, 0, stream>>>(ws, out, K);
    pt16_prep<<<dim3(8, 64), 256, 0, stream>>>(hp1, hp2, ws, K);
    qkv_gemv<<<dim3(6, 128), 256, 0, stream>>>(hidden, Wq, Wk, Wv, ws);
    qhash_kernel<<<NH, 128, 0, stream>>>(hp1, hb1, hp2, hb2, ws, S);
    key_kernel<<<dim3((K + 63) / 64, NH), 256, 0, stream>>>(key_cache, hb1, hb2, ws, S);
    select_kernel<<<NH, 256, 0, stream>>>(ws, S, nrem);
    gather_kernel<<<dim3(NH, 8), 256, 0, stream>>>(val_cache, ws, S, nrem);
    out_gemv<<<dim3(4, 128), 256, 0, stream>>>(Wo, ws, out, K);
}

// Round 4
// 346.542 us; speedup vs baseline: 1.7930x; 1.0888x over previous
//
#include <hip/hip_runtime.h>
#include <math.h>

#define NH 32
#define NKVH 8
#define HD 128

typedef _Float16 half8 __attribute__((ext_vector_type(8)));
typedef float f32x4 __attribute__((ext_vector_type(4)));

// ws layout (float elements):
#define OFF_QPROJ 0        // 4096 q | 1024 k | 1024 v
#define OFF_KNEW  4096
#define OFF_VNEW  5120
#define OFF_QR    6144     // 4096
#define OFF_QHASH 10240    // 128 (32x u32)
#define OFF_TAB   10368    // cos K*64 | sin K*64
// OFF_SCORES = OFF_TAB + 2*K*64        (NH*K floats)
// OFF_DRAFT  = OFF_SCORES + NH*K       (NH*K int)
// OFF_ATTN   = OFF_DRAFT + NH*K        (4096)
// OFF_SELIDX = OFF_ATTN + 4096         (NH*512 int)
// OFF_SELW   = OFF_SELIDX + NH*512     (NH*512)
// OFF_PT16   = OFF_SELW + NH*512       (NH*2*16384 fp16)

// combined: rope tables + zero-init (blocks < nInit), PT16 weight transpose
// (blocks >= nInit). PT16[h][mat][ks(4)][nt(8)][lane(64)][j(8)] =
// P[h][k=ks*32+(lane>>4)*8+j][n=nt*16+(lane&15)]
__global__ void init_kernel(const float* __restrict__ hp1, const float* __restrict__ hp2,
                            float* __restrict__ ws, float* __restrict__ out,
                            int K, int nInit) {
    const int tid = threadIdx.x;
    if ((int)blockIdx.x < nInit) {
        int idx = blockIdx.x * 256 + tid;
        if (idx < K * 64) {
            int pos = idx >> 6, d = idx & 63;
            double inv = exp(-((double)d / 64.0) * log(10000.0));
            double ang = (double)pos * inv;
            double s, c;
            sincos(ang, &s, &c);
            ws[OFF_TAB + idx]                  = (float)c;
            ws[OFF_TAB + (size_t)K * 64 + idx] = (float)s;
        }
        if (idx < 6144) ws[OFF_QPROJ + idx] = 0.f;
        if (idx < 4096) out[idx] = 0.f;
        size_t off_attn = OFF_TAB + 2 * (size_t)K * 64 + 2 * (size_t)NH * K;
        if (idx < 4096) ws[off_attn + idx] = 0.f;
    } else {
        int id = blockIdx.x - nInit;          // 0..511
        int h2 = id >> 3;                     // 0..63  (h*2+mat)
        int tg = (id & 7) * 256 + tid;        // 0..2047
        const int lane = tg & 63, nt = (tg >> 6) & 7, ks = tg >> 9;
        const int kbase = ks * 32 + ((tg >> 4) & 3) * 8;
        const int n = nt * 16 + (tg & 15);
        const float* P = ((h2 & 1) ? hp2 : hp1) + (size_t)(h2 >> 1) * 16384;
        half8 v;
#pragma unroll
        for (int j = 0; j < 8; ++j) v[j] = (_Float16)P[(size_t)(kbase + j) * 128 + n];
        size_t off_pt = OFF_TAB + 2 * (size_t)K * 64 + 2 * (size_t)NH * K + 4096 + 2 * (size_t)NH * 512;
        ((half8*)(ws + off_pt))[(size_t)h2 * 2048 + tg] = v;
    }
}

// hidden(4096) @ [Wq|Wk|Wv] -> qproj(6144). float4 cols, 64-row split-K, atomics.
__global__ __launch_bounds__(256) void qkv_gemv(const float* __restrict__ hidden,
        const float* __restrict__ Wq, const float* __restrict__ Wk,
        const float* __restrict__ Wv, float* __restrict__ ws) {
    __shared__ float hs[64];
    const int tid = threadIdx.x;
    const int col = (blockIdx.x * 256 + tid) * 4;
    const int i0  = blockIdx.y * 64;
    if (tid < 64) hs[tid] = hidden[i0 + tid];
    __syncthreads();
    const float* W; int ld, wcol;
    if (col < 4096)      { W = Wq; ld = 4096; wcol = col; }
    else if (col < 5120) { W = Wk; ld = 1024; wcol = col - 4096; }
    else                 { W = Wv; ld = 1024; wcol = col - 5120; }
    const float* p = W + (size_t)i0 * ld + wcol;
    float4 a0 = {0.f,0.f,0.f,0.f}, a1 = {0.f,0.f,0.f,0.f};
#pragma unroll 4
    for (int ii = 0; ii < 64; ii += 2) {
        float4 w0 = *(const float4*)p;
        float4 w1 = *(const float4*)(p + ld);
        float h0 = hs[ii], h1 = hs[ii + 1];
        a0.x = fmaf(h0, w0.x, a0.x); a0.y = fmaf(h0, w0.y, a0.y);
        a0.z = fmaf(h0, w0.z, a0.z); a0.w = fmaf(h0, w0.w, a0.w);
        a1.x = fmaf(h1, w1.x, a1.x); a1.y = fmaf(h1, w1.y, a1.y);
        a1.z = fmaf(h1, w1.z, a1.z); a1.w = fmaf(h1, w1.w, a1.w);
        p += 2 * (size_t)ld;
    }
    atomicAdd(&ws[OFF_QPROJ + col + 0], a0.x + a1.x);
    atomicAdd(&ws[OFF_QPROJ + col + 1], a0.y + a1.y);
    atomicAdd(&ws[OFF_QPROJ + col + 2], a0.z + a1.z);
    atomicAdd(&ws[OFF_QPROJ + col + 3], a0.w + a1.w);
}

// per head: rope(q), hash(q) in fp32, pack sign bits
__global__ __launch_bounds__(128) void qhash_kernel(const float* __restrict__ hp1,
        const float* __restrict__ hb1, const float* __restrict__ hp2,
        const float* __restrict__ hb2, float* __restrict__ ws, int S) {
    const int h = blockIdx.x, d = threadIdx.x;
    const int K = S + 1;
    __shared__ float X[128], H1[128];
    float q  = ws[OFF_QPROJ + h * 128 + d];
    float qp = ws[OFF_QPROJ + h * 128 + (d ^ 64)];
    const float* cosT = ws + OFF_TAB;
    const float* sinT = cosT + (size_t)K * 64;
    float cs = cosT[(size_t)S * 64 + (d & 63)];
    float sn = sinT[(size_t)S * 64 + (d & 63)];
    float r = (d < 64) ? -qp : qp;
    float qr = q * cs + r * sn;
    X[d] = qr;
    ws[OFF_QR + h * 128 + d] = qr;
    __syncthreads();
    const float* P1 = hp1 + (size_t)h * 16384;
    float t = hb1[h * 128 + d];
    for (int i = 0; i < 128; ++i) t = fmaf(X[i], P1[i * 128 + d], t);
    float u = t / (1.f + expf(-t)) + X[d];
    H1[d] = u;
    __syncthreads();
    const float* P2 = hp2 + (size_t)h * 16384;
    float t2 = hb2[h * 128 + d] + u;
    for (int i = 0; i < 128; ++i) t2 = fmaf(H1[i], P2[i * 128 + d], t2);
    unsigned long long bal = __ballot(t2 > 0.f);
    if ((d & 63) == 0)
        ((unsigned long long*)(ws + OFF_QHASH))[h * 2 + (d >> 6)] = bal;
}

// MFMA key kernel, barrier-free: 64 keys/block, everything wave-local.
// rope(fp32) -> scores(fp32) -> GEMM1/2 via mfma_f32_16x16x32_f16 with B
// fragments loaded straight from L2 -> ballot sign-pack -> popcount draft.
__global__ __launch_bounds__(256, 3) void key_kernel(const float* __restrict__ key_cache,
        const float* __restrict__ hb1, const float* __restrict__ hb2,
        float* __restrict__ ws, int S) {
    const int K  = S + 1;
    const int h  = blockIdx.y;
    const int k0 = blockIdx.x * 64;
    const int tid = threadIdx.x;
    const int wv = tid >> 6, lane = tid & 63;
    const int m = lane & 15, quad = lane >> 4;

    __shared__ float    XF[64 * 132];      // fp32 rotated keys / h1 residual
    __shared__ _Float16 XH[64 * 136];      // fp16 A-operand copy

    const float* cosT = ws + OFF_TAB;
    const float* sinT = cosT + (size_t)K * 64;
    float* scores = ws + OFF_TAB + 2 * (size_t)K * 64;
    int*   draft  = (int*)(scores + (size_t)NH * K);
    size_t off_pt = OFF_TAB + 2 * (size_t)K * 64 + 2 * (size_t)NH * K + 4096 + 2 * (size_t)NH * 512;
    const half8* PT1 = (const half8*)((const _Float16*)(ws + off_pt) + (size_t)(h * 2) * 16384);
    const half8* PT2 = PT1 + 2048;

    // ---- rope: thread = (key = tid>>2, qq = tid&3) — wave wv owns keys wv*16..+15
    const int key = tid >> 2, qq = tid & 3, d0 = qq * 16;
    const int kg = k0 + key;
    float lo[16], hi[16];
    if (kg < K) {
        const float* row = (kg < S) ? key_cache + ((size_t)h * S + kg) * 128
                                    : ws + OFF_KNEW + (h >> 2) * 128;
#pragma unroll
        for (int i4 = 0; i4 < 4; ++i4) {
            float4 xa = *(const float4*)(row + d0 + i4 * 4);
            float4 xb = *(const float4*)(row + 64 + d0 + i4 * 4);
            float4 cc = *(const float4*)(cosT + (size_t)kg * 64 + d0 + i4 * 4);
            float4 ss = *(const float4*)(sinT + (size_t)kg * 64 + d0 + i4 * 4);
            lo[i4*4+0] = xa.x * cc.x - xb.x * ss.x;  hi[i4*4+0] = xb.x * cc.x + xa.x * ss.x;
            lo[i4*4+1] = xa.y * cc.y - xb.y * ss.y;  hi[i4*4+1] = xb.y * cc.y + xa.y * ss.y;
            lo[i4*4+2] = xa.z * cc.z - xb.z * ss.z;  hi[i4*4+2] = xb.z * cc.z + xa.z * ss.z;
            lo[i4*4+3] = xa.w * cc.w - xb.w * ss.w;  hi[i4*4+3] = xb.w * cc.w + xa.w * ss.w;
        }
    } else {
#pragma unroll
        for (int i = 0; i < 16; ++i) { lo[i] = 0.f; hi[i] = 0.f; }
    }
#pragma unroll
    for (int i4 = 0; i4 < 4; ++i4) {
        float4 l4 = {lo[i4*4], lo[i4*4+1], lo[i4*4+2], lo[i4*4+3]};
        float4 h4 = {hi[i4*4], hi[i4*4+1], hi[i4*4+2], hi[i4*4+3]};
        *(float4*)&XF[key * 132 + d0 + i4 * 4]      = l4;
        *(float4*)&XF[key * 132 + 64 + d0 + i4 * 4] = h4;
    }
    {
        half8 hl0, hl1, hh0, hh1;
#pragma unroll
        for (int i = 0; i < 8; ++i) {
            hl0[i] = (_Float16)lo[i];     hl1[i] = (_Float16)lo[8 + i];
            hh0[i] = (_Float16)hi[i];     hh1[i] = (_Float16)hi[8 + i];
        }
        *(half8*)&XH[key * 136 + d0]          = hl0;
        *(half8*)&XH[key * 136 + d0 + 8]      = hl1;
        *(half8*)&XH[key * 136 + 64 + d0]     = hh0;
        *(half8*)&XH[key * 136 + 64 + d0 + 8] = hh1;
    }

    // ---- true attention scores (fp32, registers; q straight from L2) ----
    {
        const float* qr = ws + OFF_QR + h * 128;
        float part = 0.f;
#pragma unroll
        for (int i4 = 0; i4 < 4; ++i4) {
            float4 qa = *(const float4*)(qr + d0 + i4 * 4);
            float4 qb = *(const float4*)(qr + 64 + d0 + i4 * 4);
            part = fmaf(qa.x, lo[i4*4+0], fmaf(qb.x, hi[i4*4+0], part));
            part = fmaf(qa.y, lo[i4*4+1], fmaf(qb.y, hi[i4*4+1], part));
            part = fmaf(qa.z, lo[i4*4+2], fmaf(qb.z, hi[i4*4+2], part));
            part = fmaf(qa.w, lo[i4*4+3], fmaf(qb.w, hi[i4*4+3], part));
        }
        part += __shfl_xor(part, 1);
        part += __shfl_xor(part, 2);
        if (qq == 0 && kg < K) scores[(size_t)h * K + kg] = part * 0.08838834764831845f;
    }

    float b1v[8], b2v[8];
#pragma unroll
    for (int nt = 0; nt < 8; ++nt) {
        b1v[nt] = hb1[h * 128 + nt * 16 + m];
        b2v[nt] = hb2[h * 128 + nt * 16 + m];
    }
    unsigned short qh16[8];
    {
        uint4 q4 = *(const uint4*)((const unsigned*)(ws + OFF_QHASH) + h * 4);
        unsigned qa[4] = {q4.x, q4.y, q4.z, q4.w};
#pragma unroll
        for (int nt = 0; nt < 8; ++nt)
            qh16[nt] = (unsigned short)((qa[nt >> 1] >> ((nt & 1) * 16)) & 0xFFFFu);
    }

    f32x4 acc[8];

#define GEMM_MFMA(PT)                                                              \
    {                                                                              \
        _Pragma("unroll") for (int nt = 0; nt < 8; ++nt)                           \
            acc[nt] = (f32x4){0.f, 0.f, 0.f, 0.f};                                 \
        _Pragma("unroll") for (int c = 0; c < 4; ++c) {                            \
            half8 afrag = *(const half8*)&XH[(wv * 16 + m) * 136 + c * 32 + quad * 8]; \
            _Pragma("unroll") for (int nt = 0; nt < 8; ++nt) {                     \
                half8 bfrag = (PT)[c * 512 + nt * 64 + lane];                      \
                acc[nt] = __builtin_amdgcn_mfma_f32_16x16x32_f16(afrag, bfrag, acc[nt], 0, 0, 0); \
            }                                                                      \
        }                                                                          \
    }

    // ---- GEMM1: t1 = X@P1 ; h1 = silu(t1+b1) + x (wave-local rows) ----
    GEMM_MFMA(PT1)
#pragma unroll
    for (int nt = 0; nt < 8; ++nt) {
        const int n = nt * 16 + m;
#pragma unroll
        for (int r = 0; r < 4; ++r) {
            const int kk = wv * 16 + quad * 4 + r;
            float t = acc[nt][r] + b1v[nt];
            float x = XF[kk * 132 + n];
            float h1v = t / (1.f + expf(-t)) + x;
            XF[kk * 132 + n] = h1v;
            XH[kk * 136 + n] = (_Float16)h1v;
        }
    }

    // ---- GEMM2: t2 = H1@P2 + b2 + h1 ; ballot sign-pack ; popcount draft ----
    GEMM_MFMA(PT2)
    {
        int ham[4] = {0, 0, 0, 0};
#pragma unroll
        for (int nt = 0; nt < 8; ++nt) {
            const int n = nt * 16 + m;
#pragma unroll
            for (int r = 0; r < 4; ++r) {
                const int kk = wv * 16 + quad * 4 + r;
                float t2 = acc[nt][r] + b2v[nt] + XF[kk * 132 + n];
                unsigned long long bal = __ballot(t2 > 0.f);
                unsigned bits = (unsigned)(bal >> (quad * 16)) & 0xFFFFu;
                ham[r] += __popc(bits ^ (unsigned)qh16[nt]);
            }
        }
        if (m == 0) {
#pragma unroll
            for (int r = 0; r < 4; ++r) {
                int kgd = k0 + wv * 16 + quad * 4 + r;
                if (kgd < K) draft[(size_t)h * K + kgd] = 128 - 2 * ham[r];
            }
        }
    }
#undef GEMM_MFMA
}

// per head: exact stable top-k (histogram + index-ordered tie scan), write
// selected indices + softmax weights.
__global__ __launch_bounds__(256) void select_kernel(float* __restrict__ ws, int S, int nrem) {
    const int K = S + 1;
    const int h = blockIdx.x;
    const int tid = threadIdx.x;
    __shared__ int hist[129];
    __shared__ int sel_idx[512];
    __shared__ float red[256];
    __shared__ int wtot[4];
    __shared__ int sh_tval, sh_r, sh_cnt, sh_run;

    float* scoresB = ws + OFF_TAB + 2 * (size_t)K * 64;
    const int* draft = (const int*)(scoresB + (size_t)NH * K) + (size_t)h * K;
    const float* sc = scoresB + (size_t)h * K;
    float* attn = scoresB + 2 * (size_t)NH * K;
    int*   selidx_g = (int*)(attn + 4096) + h * 512;
    float* selw_g   = (attn + 4096 + NH * 512) + h * 512;

    for (int i = tid; i < 129; i += 256) hist[i] = 0;
    if (tid == 0) { sh_cnt = 0; sh_run = 0; }
    __syncthreads();
    for (int k = tid; k < K; k += 256) atomicAdd(&hist[(draft[k] + 128) >> 1], 1);
    __syncthreads();
    if (tid == 0) {
        int cum = 0, tb = 0, r = nrem;
        for (int b = 128; b >= 0; --b) {
            int c = hist[b];
            if (cum + c >= nrem) { tb = b; r = nrem - cum; break; }
            cum += c;
        }
        sh_tval = tb * 2 - 128; sh_r = r;
    }
    __syncthreads();
    const int tval = sh_tval, r = sh_r;
    const int lane = tid & 63, wave = tid >> 6;
    for (int base = 0; base < K; base += 256) {
        int k = base + tid;
        bool valid = (k < K);
        int dv = valid ? draft[k] : -1000;
        bool eq = valid && (dv == tval);
        bool gt = valid && (dv > tval);
        unsigned long long bal = __ballot(eq);
        if (lane == 0) wtot[wave] = __popcll(bal);
        __syncthreads();
        int woff = 0;
        for (int w = 0; w < wave; ++w) woff += wtot[w];
        int rank = sh_run + woff + __popcll(bal & ((1ull << lane) - 1ull));
        bool sel = gt || (eq && (rank < r));
        if (sel) sel_idx[atomicAdd(&sh_cnt, 1)] = k;
        __syncthreads();
        if (tid == 0) sh_run += wtot[0] + wtot[1] + wtot[2] + wtot[3];
        __syncthreads();
    }
    float mmax = -3.402823466e38f;
    for (int li = tid; li < nrem; li += 256) mmax = fmaxf(mmax, sc[sel_idx[li]]);
    red[tid] = mmax; __syncthreads();
    for (int s2 = 128; s2 > 0; s2 >>= 1) {
        if (tid < s2) red[tid] = fmaxf(red[tid], red[tid + s2]);
        __syncthreads();
    }
    mmax = red[0]; __syncthreads();
    float z = 0.f;
    for (int li = tid; li < nrem; li += 256) z += expf(sc[sel_idx[li]] - mmax);
    red[tid] = z; __syncthreads();
    for (int s2 = 128; s2 > 0; s2 >>= 1) {
        if (tid < s2) red[tid] += red[tid + s2];
        __syncthreads();
    }
    float Z = red[0]; __syncthreads();
    for (int li = tid; li < nrem; li += 256) {
        int idx = sel_idx[li];
        selidx_g[li] = idx;
        selw_g[li] = expf(sc[idx] - mmax) / Z;
    }
}

// weighted V gather: grid (NH,16); one wave per row (float2/lane = 512B row),
// 64 independent streams per head; atomic accum into attn.
__global__ __launch_bounds__(256) void gather_kernel(const float* __restrict__ val_cache,
        float* __restrict__ ws, int S, int nrem) {
    const int K = S + 1;
    const int h = blockIdx.x, g = blockIdx.y;
    const int tid = threadIdx.x;
    const int wave = tid >> 6, lane = tid & 63;
    const int stream = g * 4 + wave;
    float* scoresB = ws + OFF_TAB + 2 * (size_t)K * 64;
    float* attn = scoresB + 2 * (size_t)NH * K;
    const int*   selidx_g = (const int*)(attn + 4096) + h * 512;
    const float* selw_g   = (attn + 4096 + NH * 512) + h * 512;
    float ax = 0.f, ay = 0.f;
    for (int li = stream; li < nrem; li += 64) {
        int idx = selidx_g[li];
        float w = selw_g[li];
        const float* vr = (idx < S) ? val_cache + ((size_t)h * S + idx) * 128
                                    : ws + OFF_VNEW + (h >> 2) * 128;
        float2 v = ((const float2*)vr)[lane];
        ax = fmaf(w, v.x, ax);
        ay = fmaf(w, v.y, ay);
    }
    atomicAdd(&attn[h * 128 + lane * 2 + 0], ax);
    atomicAdd(&attn[h * 128 + lane * 2 + 1], ay);
}

// attn(4096) @ Wo(4096x4096) -> out. float4 cols, 64-row split-K, atomics.
__global__ __launch_bounds__(256) void out_gemv(const float* __restrict__ Wo,
        const float* __restrict__ ws, float* __restrict__ out, int K) {
    __shared__ float hs[64];
    const int tid = threadIdx.x;
    const int col = (blockIdx.x * 256 + tid) * 4;
    const int i0  = blockIdx.y * 64;
    const float* ao = ws + OFF_TAB + 2 * (size_t)K * 64 + 2 * (size_t)NH * K;
    if (tid < 64) hs[tid] = ao[i0 + tid];
    __syncthreads();
    const float* p = Wo + (size_t)i0 * 4096 + col;
    float4 a0 = {0.f,0.f,0.f,0.f}, a1 = {0.f,0.f,0.f,0.f};
#pragma unroll 4
    for (int ii = 0; ii < 64; ii += 2) {
        float4 w0 = *(const float4*)p;
        float4 w1 = *(const float4*)(p + 4096);
        float h0 = hs[ii], h1 = hs[ii + 1];
        a0.x = fmaf(h0, w0.x, a0.x); a0.y = fmaf(h0, w0.y, a0.y);
        a0.z = fmaf(h0, w0.z, a0.z); a0.w = fmaf(h0, w0.w, a0.w);
        a1.x = fmaf(h1, w1.x, a1.x); a1.y = fmaf(h1, w1.y, a1.y);
        a1.z = fmaf(h1, w1.z, a1.z); a1.w = fmaf(h1, w1.w, a1.w);
        p += 8192;
    }
    atomicAdd(&out[col + 0], a0.x + a1.x);
    atomicAdd(&out[col + 1], a0.y + a1.y);
    atomicAdd(&out[col + 2], a0.z + a1.z);
    atomicAdd(&out[col + 3], a0.w + a1.w);
}

extern "C" void kernel_launch(void* const* d_in, const int* in_sizes, int n_in,
                              void* d_out, int out_size, void* d_ws, size_t ws_size,
                              hipStream_t stream) {
    const float* hidden = (const float*)d_in[0];
    const float* key_cache = (const float*)d_in[1];
    const float* val_cache = (const float*)d_in[2];
    const float* Wq = (const float*)d_in[3];
    const float* Wk = (const float*)d_in[4];
    const float* Wv = (const float*)d_in[5];
    const float* Wo = (const float*)d_in[6];
    const float* hp1 = (const float*)d_in[7];
    const float* hb1 = (const float*)d_in[8];
    const float* hp2 = (const float*)d_in[9];
    const float* hb2 = (const float*)d_in[10];
    float* out = (float*)d_out;
    float* ws  = (float*)d_ws;

    const int S = in_sizes[1] / (NH * HD);   // 4096
    const int K = S + 1;                      // 4097
    int mn = (K < 128) ? K : 128;
    int nrem = K - (int)((double)K * 0.9);
    if (nrem < mn) nrem = mn;                 // 410

    const int nInit = (K * 64 + 255) / 256;
    init_kernel<<<nInit + 512, 256, 0, stream>>>(hp1, hp2, ws, out, K, nInit);
    qkv_gemv<<<dim3(6, 64), 256, 0, stream>>>(hidden, Wq, Wk, Wv, ws);
    qhash_kernel<<<NH, 128, 0, stream>>>(hp1, hb1, hp2, hb2, ws, S);
    key_kernel<<<dim3((K + 63) / 64, NH), 256, 0, stream>>>(key_cache, hb1, hb2, ws, S);
    select_kernel<<<NH, 256, 0, stream>>>(ws, S, nrem);
    gather_kernel<<<dim3(NH, 16), 256, 0, stream>>>(val_cache, ws, S, nrem);
    out_gemv<<<dim3(4, 64), 256, 0, stream>>>(Wo, ws, out, K);
}